// Round 5
// baseline (1540.051 us; speedup 1.0000x reference)
//
#include <hip/hip_runtime.h>
#include <hip/hip_bf16.h>
#include <math.h>

#define B_  64
#define S_  16
#define T_  48
#define E_  300
#define H_  150
#define G_  300   // 2H
#define NC_ 300
#define NW_ (B_*S_)     // 1024 word-level batch
#define RW_ (T_*NW_)    // 49152 word rows
#define RS_ (S_*B_)     // 1024 sentence rows

__device__ __forceinline__ float sigm(float x){ return 1.0f/(1.0f+__expf(-x)); }

// ---------------------------------------------------------------------------
// transpose: in[R][C] -> out[C][R]
// ---------------------------------------------------------------------------
__global__ __launch_bounds__(256) void transpose_kernel(
    const float* __restrict__ in, float* __restrict__ out, int R, int C){
  int idx = blockIdx.x*256 + threadIdx.x;
  if (idx >= R*C) return;
  int j = idx % R, e = idx / R;
  out[idx] = in[(size_t)j*C + e];   // out[e][j]
}

// ---------------------------------------------------------------------------
// Whh[2][450][150] -> Wblk[2][38][450][4] : Wblk[d][e4][j][k] = Whh[d][j][4e4+k]
// (zero-padded for e >= 150)
// ---------------------------------------------------------------------------
__global__ __launch_bounds__(256) void prep_whh_kernel(
    const float* __restrict__ Whh, float* __restrict__ Wblk){
  int idx = blockIdx.x*256 + threadIdx.x;
  if (idx >= 2*38*450*4) return;
  int k  = idx & 3;
  int j  = (idx >> 2) % 450;
  int e4 = (idx >> 2) / 450 % 38;
  int d  = idx / (38*450*4);
  int e  = e4*4 + k;
  Wblk[idx] = (e < 150) ? Whh[((size_t)d*450 + j)*150 + e] : 0.f;
}

// ---------------------------------------------------------------------------
// gi[t][n][j] = emb[docs[n,t]] @ Wih^T + bih, via K-major Wt[300][900].
// ---------------------------------------------------------------------------
__global__ __launch_bounds__(256,3) void word_gi_v2(
    const int* __restrict__ docs, const float* __restrict__ emb,
    const float* __restrict__ Wt, const float* __restrict__ bih,
    float* __restrict__ gi){
  __shared__ float A[16][304];
  __shared__ float Wc[2][4*900];
  int r0 = blockIdx.x * 16;
  int t  = r0 >> 10;
  int nb = r0 & 1023;
  for (int idx = threadIdx.x; idx < 16*75; idx += 256){
    int row = idx/75, e4 = idx - row*75;
    int tok = docs[(nb+row)*T_ + t];
    *(float4*)&A[row][e4*4] = *(const float4*)&emb[(size_t)tok*E_ + e4*4];
  }
  const float4* Wt4 = (const float4*)Wt;
  {
    float4* Wb0 = (float4*)Wc[0];
    for (int i4 = threadIdx.x; i4 < 900; i4 += 256) Wb0[i4] = Wt4[i4];
  }
  __syncthreads();
  int q = threadIdx.x;
  float acc[16][4] = {};
  float4 pf0, pf1, pf2, pf3;
  for (int c = 0; c < 75; ++c){
    int cur = c & 1;
    if (c < 74){
      const float4* src = Wt4 + (size_t)(c+1)*900;
      pf0 = src[q]; pf1 = src[q+256]; pf2 = src[q+512];
      if (q < 132) pf3 = src[q+768];
    }
    if (q < 225){
      const float4* wrow = (const float4*)Wc[cur];
      float4 w0 = wrow[q], w1 = wrow[225+q], w2 = wrow[450+q], w3 = wrow[675+q];
#pragma unroll
      for (int i = 0; i < 16; ++i){
        float4 av = *(const float4*)&A[i][c*4];
        acc[i][0] += av.x*w0.x + av.y*w1.x + av.z*w2.x + av.w*w3.x;
        acc[i][1] += av.x*w0.y + av.y*w1.y + av.z*w2.y + av.w*w3.y;
        acc[i][2] += av.x*w0.z + av.y*w1.z + av.z*w2.z + av.w*w3.z;
        acc[i][3] += av.x*w0.w + av.y*w1.w + av.z*w2.w + av.w*w3.w;
      }
    }
    if (c < 74){
      float4* Wbn = (float4*)Wc[cur^1];
      Wbn[q] = pf0; Wbn[q+256] = pf1; Wbn[q+512] = pf2;
      if (q < 132) Wbn[q+768] = pf3;
    }
    __syncthreads();
  }
  if (q < 225){
    int j0 = q*4;
    float4 bb = *(const float4*)&bih[j0];
#pragma unroll
    for (int i = 0; i < 16; ++i){
      float4 o4;
      o4.x = acc[i][0]+bb.x; o4.y = acc[i][1]+bb.y;
      o4.z = acc[i][2]+bb.z; o4.w = acc[i][3]+bb.w;
      *(float4*)&gi[((size_t)(t*NW_) + nb + i)*900 + j0] = o4;
    }
  }
}

// sentence-level gi (tiny: 64 blocks)
__global__ __launch_bounds__(256) void sent_gi_kernel(
    const float* __restrict__ sv, const float* __restrict__ Wih,
    const float* __restrict__ bih, float* __restrict__ gi){
  __shared__ float A[16][G_];
  int r0 = blockIdx.x * 16;
  int s  = r0 >> 6;
  int bb_ = r0 & 63;
  for (int idx = threadIdx.x; idx < 16*75; idx += 256){
    int row = idx / 75, e4 = idx - row*75;
    *(float4*)&A[row][e4*4] =
        *(const float4*)&sv[(((size_t)(bb_+row))*S_ + s)*G_ + e4*4];
  }
  __syncthreads();
  int q = threadIdx.x;
  if (q >= 225) return;
  int j0 = q*4;
  const float4* w0 = (const float4*)(Wih + (size_t)(j0  )*G_);
  const float4* w1 = (const float4*)(Wih + (size_t)(j0+1)*G_);
  const float4* w2 = (const float4*)(Wih + (size_t)(j0+2)*G_);
  const float4* w3 = (const float4*)(Wih + (size_t)(j0+3)*G_);
  float acc[16][4];
#pragma unroll
  for (int i=0;i<16;i++){ acc[i][0]=0.f; acc[i][1]=0.f; acc[i][2]=0.f; acc[i][3]=0.f; }
  for (int e4=0; e4<75; e4++){
    float4 b0=w0[e4], b1=w1[e4], b2=w2[e4], b3=w3[e4];
#pragma unroll
    for (int i=0;i<16;i++){
      float4 av = *(const float4*)&A[i][e4*4];
      acc[i][0] += av.x*b0.x + av.y*b0.y + av.z*b0.z + av.w*b0.w;
      acc[i][1] += av.x*b1.x + av.y*b1.y + av.z*b1.z + av.w*b1.w;
      acc[i][2] += av.x*b2.x + av.y*b2.y + av.z*b2.z + av.w*b2.w;
      acc[i][3] += av.x*b3.x + av.y*b3.y + av.z*b3.z + av.w*b3.w;
    }
  }
  float4 bb = *(const float4*)&bih[j0];
#pragma unroll
  for (int i=0;i<16;i++){
    float4 o4;
    o4.x = acc[i][0]+bb.x; o4.y = acc[i][1]+bb.y;
    o4.z = acc[i][2]+bb.z; o4.w = acc[i][3]+bb.w;
    *(float4*)&gi[((size_t)(s*B_) + bb_ + i)*900 + j0] = o4;
  }
}

// ---------------------------------------------------------------------------
// GRU scan v2: block = (R rows, 1 direction); thread (h, g) computes gate
// columns {h,150+h,300+h} for 2 rows (i=2g,2g+1), accumulators + h in
// registers; h double-buffered in LDS (broadcast reads); Wblk coalesced.
// One barrier per step.
// ---------------------------------------------------------------------------
template<int R, int TPB>
__global__ __launch_bounds__(TPB) void gru_scan_v2(
    const float* __restrict__ gi, const float* __restrict__ Wblk,
    const float* __restrict__ bhh, float* __restrict__ hs,
    int T, int N){
  constexpr int ACT = (R/2)*150;
  int d  = blockIdx.y;
  int n0 = blockIdx.x * R;
  __shared__ float hl[2][R][152];
  int tid = threadIdx.x;
  for (int idx = tid; idx < 2*R*152; idx += TPB) (&hl[0][0][0])[idx] = 0.f;
  __syncthreads();
  bool act = tid < ACT;
  int g = tid/150, h = tid - g*150;
  int i0 = 2*g, i1 = 2*g+1;
  const float4* Wb4 = (const float4*)(Wblk + (size_t)d*38*1800);
  float br=0.f, bz=0.f, bn=0.f;
  if (act){
    br = bhh[d*450 + h];
    bz = bhh[d*450 + 150 + h];
    bn = bhh[d*450 + 300 + h];
  }
  float h0r = 0.f, h1r = 0.f;   // register copies of h[i0][h], h[i1][h]
  int buf = 0;
  for (int step = 0; step < T; ++step){
    int t = d ? (T-1-step) : step;
    const float* gib = gi + ((size_t)t*N + n0)*900 + d*450;
    float p0r=0,p0z=0,p0n=0,p1r=0,p1z=0,p1n=0;
    if (act){
      p0r = gib[(size_t)i0*900 + h];
      p0z = gib[(size_t)i0*900 + 150 + h];
      p0n = gib[(size_t)i0*900 + 300 + h];
      p1r = gib[(size_t)i1*900 + h];
      p1z = gib[(size_t)i1*900 + 150 + h];
      p1n = gib[(size_t)i1*900 + 300 + h];
    }
    float ar0=0,az0=0,an0=0,ar1=0,az1=0,an1=0;
    if (act){
      const float4* h04 = (const float4*)hl[buf][i0];
      const float4* h14 = (const float4*)hl[buf][i1];
#pragma unroll 2
      for (int e4 = 0; e4 < 38; ++e4){
        float4 wr = Wb4[e4*450 + h];
        float4 wz = Wb4[e4*450 + 150 + h];
        float4 wn = Wb4[e4*450 + 300 + h];
        float4 a = h04[e4], b = h14[e4];
        ar0 += wr.x*a.x + wr.y*a.y + wr.z*a.z + wr.w*a.w;
        az0 += wz.x*a.x + wz.y*a.y + wz.z*a.z + wz.w*a.w;
        an0 += wn.x*a.x + wn.y*a.y + wn.z*a.z + wn.w*a.w;
        ar1 += wr.x*b.x + wr.y*b.y + wr.z*b.z + wr.w*b.w;
        az1 += wz.x*b.x + wz.y*b.y + wz.z*b.z + wz.w*b.w;
        an1 += wn.x*b.x + wn.y*b.y + wn.z*b.z + wn.w*b.w;
      }
      float r0 = sigm(p0r + ar0 + br);
      float z0 = sigm(p0z + az0 + bz);
      float nn0 = tanhf(p0n + r0*(an0 + bn));
      float h20 = (1.f - z0)*nn0 + z0*h0r;
      h0r = h20;
      hl[buf^1][i0][h] = h20;
      hs[((size_t)t*N + n0 + i0)*G_ + d*H_ + h] = h20;
      float r1 = sigm(p1r + ar1 + br);
      float z1 = sigm(p1z + az1 + bz);
      float nn1 = tanhf(p1n + r1*(an1 + bn));
      float h21 = (1.f - z1)*nn1 + z1*h1r;
      h1r = h21;
      hl[buf^1][i1][h] = h21;
      hs[((size_t)t*N + n0 + i1)*G_ + d*H_ + h] = h21;
    }
    buf ^= 1;
    __syncthreads();
  }
}

// ---------------------------------------------------------------------------
// score[r] = ctx . tanh(hs[r] @ W^T + b) via K-major Wt[300][300].
// ---------------------------------------------------------------------------
__global__ __launch_bounds__(256,2) void att_score_v2(
    const float* __restrict__ hs, const float* __restrict__ Wt,
    const float* __restrict__ bias, const float* __restrict__ ctx,
    float* __restrict__ score, int Rtot){
  __shared__ float A[48][304];
  __shared__ float Wc[2][4*300];
  int r0 = blockIdx.x * 48;
  for (int idx = threadIdx.x; idx < 48*75; idx += 256){
    int row = idx/75, e4 = idx - row*75;
    float4 v; v.x=0.f; v.y=0.f; v.z=0.f; v.w=0.f;
    if (r0 + row < Rtot) v = *(const float4*)&hs[(size_t)(r0+row)*G_ + e4*4];
    *(float4*)&A[row][e4*4] = v;
  }
  const float4* Wt4 = (const float4*)Wt;
  {
    float4* Wb0 = (float4*)Wc[0];
    for (int i4 = threadIdx.x; i4 < 300; i4 += 256) Wb0[i4] = Wt4[i4];
  }
  __syncthreads();
  int tid = threadIdx.x;
  int rg = tid/75, q = tid - rg*75;
  float acc[16][4] = {};
  float4 pf0, pf1;
  for (int c = 0; c < 75; ++c){
    int cur = c & 1;
    if (c < 74){
      const float4* src = Wt4 + (size_t)(c+1)*300;
      pf0 = src[tid];
      if (tid < 44) pf1 = src[tid+256];
    }
    if (tid < 225){
      const float4* wrow = (const float4*)Wc[cur];
      float4 w0 = wrow[q], w1 = wrow[75+q], w2 = wrow[150+q], w3 = wrow[225+q];
      const float* Ab = &A[rg*16][0];
#pragma unroll
      for (int i = 0; i < 16; ++i){
        float4 av = *(const float4*)&Ab[(size_t)i*304 + c*4];
        acc[i][0] += av.x*w0.x + av.y*w1.x + av.z*w2.x + av.w*w3.x;
        acc[i][1] += av.x*w0.y + av.y*w1.y + av.z*w2.y + av.w*w3.y;
        acc[i][2] += av.x*w0.z + av.y*w1.z + av.z*w2.z + av.w*w3.z;
        acc[i][3] += av.x*w0.w + av.y*w1.w + av.z*w2.w + av.w*w3.w;
      }
    }
    if (c < 74){
      float4* Wbn = (float4*)Wc[cur^1];
      Wbn[tid] = pf0;
      if (tid < 44) Wbn[tid+256] = pf1;
    }
    __syncthreads();
  }
  float part[16];
  if (tid < 225){
    int h0 = q*4;
    float4 bb = *(const float4*)&bias[h0];
    float4 cx = *(const float4*)&ctx[h0];
#pragma unroll
    for (int i = 0; i < 16; ++i){
      part[i] = cx.x*tanhf(acc[i][0]+bb.x) + cx.y*tanhf(acc[i][1]+bb.y)
              + cx.z*tanhf(acc[i][2]+bb.z) + cx.w*tanhf(acc[i][3]+bb.w);
    }
  }
  __syncthreads();
  float* Af = &A[0][0];
  if (tid < 225){
#pragma unroll
    for (int i = 0; i < 16; ++i) Af[q*48 + rg*16 + i] = part[i];
  }
  __syncthreads();
  if (tid < 48 && r0 + tid < Rtot){
    float s = 0.f;
    for (int q2 = 0; q2 < 75; ++q2) s += Af[q2*48 + tid];
    score[r0 + tid] = s;
  }
}

// softmax over t (per n) + weighted sum
__global__ __launch_bounds__(256) void att_combine_kernel(
    const float* __restrict__ score, const float* __restrict__ hs,
    float* __restrict__ out, int T, int N){
  int n = blockIdx.x;
  __shared__ float wa[64];
  if (threadIdx.x < T) wa[threadIdx.x] = score[threadIdx.x*N + n];
  __syncthreads();
  float m = -1e30f;
  for (int t=0;t<T;t++) m = fmaxf(m, wa[t]);
  float den = 0.f;
  for (int t=0;t<T;t++) den += __expf(wa[t]-m);
  float inv = 1.f/den;
  __syncthreads();
  if (threadIdx.x < T) wa[threadIdx.x] = __expf(wa[threadIdx.x]-m)*inv;
  __syncthreads();
  for (int g = threadIdx.x; g < G_; g += 256){
    float acc = 0.f;
    for (int t=0;t<T;t++) acc += wa[t] * hs[((size_t)t*N+n)*G_ + g];
    out[(size_t)n*G_ + g] = acc;
  }
}

// one wave per (b,k): both cosine sims
__global__ __launch_bounds__(256) void cossim_kernel(
    const int* __restrict__ cand, const int* __restrict__ sens,
    const float* __restrict__ ent, const float* __restrict__ sv,
    const float* __restrict__ odoc, float* __restrict__ sim){
  int w = (blockIdx.x*256 + threadIdx.x) >> 6;
  int lane = threadIdx.x & 63;
  if (w >= B_*NC_) return;
  int b = w / NC_, k = w - b*NC_;
  const float* c  = ent + (size_t)cand[b*NC_ + k]*E_;
  const float* a1 = sv  + ((size_t)b*S_ + sens[b])*G_;
  const float* a2 = odoc + (size_t)b*G_;
  float d1=0.f,d2=0.f,cc=0.f,n1=0.f,n2=0.f;
  for (int e = lane; e < E_; e += 64){
    float cv=c[e], v1=a1[e], v2=a2[e];
    d1+=v1*cv; d2+=v2*cv; cc+=cv*cv; n1+=v1*v1; n2+=v2*v2;
  }
  for (int off=32; off; off>>=1){
    d1+=__shfl_xor(d1,off); d2+=__shfl_xor(d2,off); cc+=__shfl_xor(cc,off);
    n1+=__shfl_xor(n1,off); n2+=__shfl_xor(n2,off);
  }
  if (lane == 0){
    float nc = sqrtf(cc);
    sim[(size_t)b*600 + k]       = d1 / fmaxf(sqrtf(n1)*nc, 1e-8f);
    sim[(size_t)b*600 + 300 + k] = d2 / fmaxf(sqrtf(n2)*nc, 1e-8f);
  }
}

// score = sim @ linW^T + linb; gold gather; argmax (first-max tie rule)
__global__ __launch_bounds__(256) void final_kernel(
    const float* __restrict__ sim, const float* __restrict__ linW,
    const float* __restrict__ linb, const int* __restrict__ idx,
    float* __restrict__ out){
  int b = blockIdx.x;
  __shared__ float ss[600];
  __shared__ float sc[300];
  __shared__ float bv[256];
  __shared__ int   bi[256];
  for (int j = threadIdx.x; j < 600; j += 256) ss[j] = sim[(size_t)b*600 + j];
  __syncthreads();
  float bestv = -1e30f; int besti = 0;
  for (int i = threadIdx.x; i < 300; i += 256){
    const float4* wr = (const float4*)(linW + (size_t)i*600);
    float acc = linb[i];
    for (int j4=0; j4<150; j4++){
      float4 w = wr[j4];
      int j = j4*4;
      acc += w.x*ss[j] + w.y*ss[j+1] + w.z*ss[j+2] + w.w*ss[j+3];
    }
    sc[i] = acc;
    out[64 + (size_t)b*300 + i] = acc;
    if (acc > bestv){ bestv = acc; besti = i; }
  }
  bv[threadIdx.x] = bestv; bi[threadIdx.x] = besti;
  __syncthreads();
  for (int s=128; s; s>>=1){
    if (threadIdx.x < s){
      float ov = bv[threadIdx.x+s]; int oi = bi[threadIdx.x+s];
      if (ov > bv[threadIdx.x] || (ov == bv[threadIdx.x] && oi < bi[threadIdx.x])){
        bv[threadIdx.x] = ov; bi[threadIdx.x] = oi;
      }
    }
    __syncthreads();
  }
  if (threadIdx.x == 0){
    out[b] = sc[idx[b]-1];
    out[64 + 64*300 + b] = (float)bi[0];
  }
}

extern "C" void kernel_launch(void* const* d_in, const int* in_sizes, int n_in,
                              void* d_out, int out_size, void* d_ws, size_t ws_size,
                              hipStream_t stream){
  const int*   docs  = (const int*)d_in[0];
  const int*   sens  = (const int*)d_in[1];
  const int*   cand  = (const int*)d_in[2];
  const int*   idx   = (const int*)d_in[3];
  const float* wemb  = (const float*)d_in[4];
  const float* eemb  = (const float*)d_in[5];
  const float* Wih_w = (const float*)d_in[6];
  const float* Whh_w = (const float*)d_in[7];
  const float* bih_w = (const float*)d_in[8];
  const float* bhh_w = (const float*)d_in[9];
  const float* attW_w= (const float*)d_in[10];
  const float* attb_w= (const float*)d_in[11];
  const float* ctx_w = (const float*)d_in[12];
  const float* Wih_s = (const float*)d_in[13];
  const float* Whh_s = (const float*)d_in[14];
  const float* bih_s = (const float*)d_in[15];
  const float* bhh_s = (const float*)d_in[16];
  const float* attW_s= (const float*)d_in[17];
  const float* attb_s= (const float*)d_in[18];
  const float* ctx_s = (const float*)d_in[19];
  const float* linW  = (const float*)d_in[20];
  const float* linb  = (const float*)d_in[21];

  float* ws = (float*)d_ws;
  size_t off = 0;
  float* gi_w    = ws + off; off += (size_t)T_*NW_*900;   // 176.9 MB
  float* hs_w    = ws + off; off += (size_t)T_*NW_*G_;    // 59 MB
  float* score_w = ws + off; off += (size_t)T_*NW_;
  float* sv      = ws + off; off += (size_t)NW_*G_;
  float* gi_s    = ws + off; off += (size_t)S_*B_*900;
  float* hs_s    = ws + off; off += (size_t)S_*B_*G_;
  float* score_s = ws + off; off += (size_t)S_*B_;
  float* odoc    = ws + off; off += (size_t)B_*G_;
  float* sim     = ws + off; off += (size_t)B_*600;
  float* Wt_w    = ws + off; off += (size_t)900*300;      // [300][900]
  float* WtA_w   = ws + off; off += (size_t)300*300;
  float* WtA_s   = ws + off; off += (size_t)300*300;
  float* Wblk_w  = ws + off; off += (size_t)2*38*450*4;   // tiled Whh (word)
  float* Wblk_s  = ws + off; off += (size_t)2*38*450*4;   // tiled Whh (sent)

  float* out = (float*)d_out;

  // one-time weight preps
  transpose_kernel<<<(900*300+255)/256, 256, 0, stream>>>(Wih_w, Wt_w, 900, 300);
  transpose_kernel<<<(300*300+255)/256, 256, 0, stream>>>(attW_w, WtA_w, 300, 300);
  transpose_kernel<<<(300*300+255)/256, 256, 0, stream>>>(attW_s, WtA_s, 300, 300);
  prep_whh_kernel<<<(2*38*450*4+255)/256, 256, 0, stream>>>(Whh_w, Wblk_w);
  prep_whh_kernel<<<(2*38*450*4+255)/256, 256, 0, stream>>>(Whh_s, Wblk_s);

  // word level
  word_gi_v2<<<RW_/16, 256, 0, stream>>>(docs, wemb, Wt_w, bih_w, gi_w);
  gru_scan_v2<8,640><<<dim3(NW_/8, 2), 640, 0, stream>>>(gi_w, Wblk_w, bhh_w,
                                                         hs_w, T_, NW_);
  att_score_v2<<<(RW_+47)/48, 256, 0, stream>>>(hs_w, WtA_w, attb_w,
                                                ctx_w, score_w, RW_);
  att_combine_kernel<<<NW_, 256, 0, stream>>>(score_w, hs_w, sv, T_, NW_);

  // sentence level
  sent_gi_kernel<<<RS_/16, 256, 0, stream>>>(sv, Wih_s, bih_s, gi_s);
  gru_scan_v2<4,320><<<dim3(B_/4, 2), 320, 0, stream>>>(gi_s, Wblk_s, bhh_s,
                                                        hs_s, S_, B_);
  att_score_v2<<<(RS_+47)/48, 256, 0, stream>>>(hs_s, WtA_s, attb_s,
                                                ctx_s, score_s, RS_);
  att_combine_kernel<<<B_, 256, 0, stream>>>(score_s, hs_s, odoc, S_, B_);

  // similarity + linear + gold + argmax
  cossim_kernel<<<(B_*NC_*64)/256, 256, 0, stream>>>(cand, sens, eemb, sv, odoc, sim);
  final_kernel<<<B_, 256, 0, stream>>>(sim, linW, linb, idx, out);
}